// Round 16
// baseline (128.241 us; speedup 1.0000x reference)
//
#include <hip/hip_runtime.h>
#include <hip/hip_cooperative_groups.h>

namespace cg = cooperative_groups;

#define D 64
#define K 1024
#define NVEC 65536
#define MB 128            // vectors per block
#define NBLK (NVEC / MB)  // 512 blocks = exactly 2/CU co-resident
#define WAVES 4
#define KPW (K / WAVES)   // 256 codes per wave
#define TILES (KPW / 16)  // 16
#define NG (MB / 16)      // 8 vector groups
#define RING 2            // r13: depth>2 is null

typedef __attribute__((ext_vector_type(8))) short bf16x8;
typedef __attribute__((ext_vector_type(4))) float f32x4;

// single v_perm_b32: {hi16(b), hi16(a)} == bf16x2(trunc(a), trunc(b))
__device__ inline unsigned pk2t(float a, float b) {
    return __builtin_amdgcn_perm(__builtin_bit_cast(unsigned, b),
                                 __builtin_bit_cast(unsigned, a), 0x07060302u);
}
__device__ inline int max3i(int a, int b, int c) {   // -> v_max3_i32
    const int m = a > b ? a : b;
    return m > c ? m : c;
}

// ---------------------------------------------------------------------------
// Single cooperative kernel:
//   phase 0: codebook f32->bf16 + norms (2 rows/block, overlapped with z stage)
//   grid.sync()
//   phase 1: r11's proven MFMA score GEMM + packed argmax + output + partial
//   grid.sync()
//   phase 2: block 0 reduces partials -> loss
// ---------------------------------------------------------------------------
__global__ __launch_bounds__(256, 2) void vq_coop(const float* __restrict__ z,
                                                  const float* __restrict__ emb,
                                                  unsigned* __restrict__ ebf_u,
                                                  float* __restrict__ hb,
                                                  float* __restrict__ out,
                                                  float* __restrict__ pP) {
    cg::grid_group grid = cg::this_grid();

    __shared__ __align__(16) char zl[MB * 128];   // 16 KB bf16 z-tile [v][d], XOR-swizzled
    __shared__ int   wv[WAVES * MB];              // 2 KB
    __shared__ int   fin[MB];
    __shared__ float redw[WAVES];
    __shared__ float red2[256];

    const int tid = threadIdx.x;
    const int blk = blockIdx.x;
    const int b   = blk >> 3;              // batch (8 blocks per batch)
    const int hw0 = (blk & 7) * MB;        // first spatial pos
    const float* zb = z + (size_t)b * (D * 1024) + hw0;

    const int wave = tid >> 6;
    const int lane = tid & 63;
    const int cw   = wave * KPW;
    const int l16  = lane & 15;
    const int lg   = lane >> 4;    // 0..3

    // ---- phase 0: codebook prep, 2 rows per block (threads 0..63, 32/row)
    if (tid < 64) {
        const int r = blk * 2 + (tid >> 5);              // 0..1023
        const int j = tid & 31;                          // f32-pair within row
        const float2 v = *reinterpret_cast<const float2*>(emb + (size_t)r * D + j * 2);
        ebf_u[(size_t)r * 32 + j] = pk2t(v.x, v.y);
        float s = fmaf(v.x, v.x, v.y * v.y);
#pragma unroll
        for (int off = 1; off < 32; off <<= 1) s += __shfl_xor(s, off, 64);
        if (j == 0) hb[r] = 1.0f - 0.5f * s;
    }

    // ---- z staging (independent of prep; overlaps its latency):
    //      f32 [d][v] -> LDS bf16 [v][d] swizzled; f32 sum(z^2)
    float zacc = 0.f;
#pragma unroll
    for (int it = 0; it < 2; ++it) {
        const int item = it * 256 + tid;   // 0..511
        const int v4 = item & 31;          // 4-vector group (128 v)
        const int d4 = item >> 5;          // 4-dim group (64 d)
        float4 r[4];
#pragma unroll
        for (int i = 0; i < 4; ++i)
            r[i] = *reinterpret_cast<const float4*>(zb + (size_t)(d4 * 4 + i) * 1024 + v4 * 4);
        const float* rf = reinterpret_cast<const float*>(r);
#pragma unroll
        for (int n = 0; n < 16; ++n) zacc = fmaf(rf[n], rf[n], zacc);
#pragma unroll
        for (int j = 0; j < 4; ++j) {
            const int v = v4 * 4 + j;
            uint2 pk;
            pk.x = pk2t(rf[0 * 4 + j], rf[1 * 4 + j]);
            pk.y = pk2t(rf[2 * 4 + j], rf[3 * 4 + j]);
            const int byte = v * 128 + ((d4 * 8) ^ ((v & 7) << 4));
            *reinterpret_cast<uint2*>(zl + byte) = pk;
        }
    }

    // ---- all codebook writes + all zl writes visible after this
    grid.sync();

    const unsigned short* ebf = (const unsigned short*)ebf_u;

    // ---- ring preload of codebook tiles 0,1
    bf16x8 A0[RING], A1[RING];
    f32x4  CI[RING];
#pragma unroll
    for (int p = 0; p < RING; ++p) {
        const unsigned short* row = ebf + (size_t)(cw + p * 16 + l16) * 64;
        A0[p] = *reinterpret_cast<const bf16x8*>(row + lg * 8);
        A1[p] = *reinterpret_cast<const bf16x8*>(row + 32 + lg * 8);
        CI[p] = *reinterpret_cast<const f32x4*>(hb + cw + p * 16 + lg * 4);
    }

    // ---- B-frags: this block's 128 vectors register-resident (64 VGPR)
    bf16x8 bfr[NG][2];
#pragma unroll
    for (int g = 0; g < NG; ++g)
#pragma unroll
        for (int h = 0; h < 2; ++h) {
            const int v = g * 16 + l16;
            const int byte = v * 128 + (((h * 64) + lg * 16) ^ ((v & 7) << 4));
            bfr[g][h] = *reinterpret_cast<const bf16x8*>(zl + byte);
        }

    // ---- k-loop: consume ring slot kt&1, prefetch kt+2, 16 MFMA, packed max3
    int best[NG];
#pragma unroll
    for (int g = 0; g < NG; ++g) best[g] = 0;

#pragma unroll 2
    for (int kt = 0; kt < TILES; ++kt) {
        const int cur = kt & (RING - 1);         // static under unroll 2
        const bf16x8 b0 = A0[cur], b1 = A1[cur];
        const f32x4  cc = CI[cur];
        const int nk = (kt + RING < TILES) ? kt + RING : kt;   // tail: harmless reload
        const unsigned short* nrow = ebf + (size_t)(cw + nk * 16 + l16) * 64;
        A0[cur] = *reinterpret_cast<const bf16x8*>(nrow + lg * 8);
        A1[cur] = *reinterpret_cast<const bf16x8*>(nrow + 32 + lg * 8);
        CI[cur] = *reinterpret_cast<const f32x4*>(hb + cw + nk * 16 + lg * 4);

        const int idx0 = cw + kt * 16 + lg * 4;
#pragma unroll
        for (int g = 0; g < NG; ++g) {
            f32x4 c = cc;
            c = __builtin_amdgcn_mfma_f32_16x16x32_bf16(b0, bfr[g][0], c, 0, 0, 0);
            c = __builtin_amdgcn_mfma_f32_16x16x32_bf16(b1, bfr[g][1], c, 0, 0, 0);
            const int p0 = (int)((__builtin_bit_cast(unsigned, c[0]) & 0xFFFFFC00u) | (unsigned)(idx0 + 0));
            const int p1 = (int)((__builtin_bit_cast(unsigned, c[1]) & 0xFFFFFC00u) | (unsigned)(idx0 + 1));
            const int p2 = (int)((__builtin_bit_cast(unsigned, c[2]) & 0xFFFFFC00u) | (unsigned)(idx0 + 2));
            const int p3 = (int)((__builtin_bit_cast(unsigned, c[3]) & 0xFFFFFC00u) | (unsigned)(idx0 + 3));
            best[g] = max3i(max3i(p0, p1, p2), p3, best[g]);   // 2x v_max3_i32
        }
    }

    // ---- cross-lane argmax (over lg groups)
#pragma unroll
    for (int g = 0; g < NG; ++g) {
        int tv = best[g];
        int o = __shfl_xor(tv, 16, 64); tv = tv > o ? tv : o;
        o = __shfl_xor(tv, 32, 64);     tv = tv > o ? tv : o;
        if (lane < 16) wv[wave * MB + g * 16 + l16] = tv;
    }
    __syncthreads();

    // ---- cross-wave combine; unpack winning score for the loss
    float tcon = 0.f;
    if (tid < MB) {
        int tv = wv[tid];
#pragma unroll
        for (int w = 1; w < WAVES; ++w) {
            const int o = wv[w * MB + tid];
            tv = tv > o ? tv : o;
        }
        fin[tid] = tv & (K - 1);
        tcon = __builtin_bit_cast(float, (unsigned)tv & 0xFFFFFC00u) - 1.0f;  // z.e - 0.5||e||^2
    }
    __syncthreads();

    // ---- output: gather exact f32 code rows, write out[b][d][hw] coalesced
    {
        const int v  = tid & 127;
        const int dh = tid >> 7;              // 0..1, 32 dims each
        const int idx = fin[v];
        const float4* eq4 = reinterpret_cast<const float4*>(emb + (size_t)idx * D + dh * 32);
        float* ob = out + (size_t)b * (D * 1024) + hw0 + v;
#pragma unroll
        for (int i = 0; i < 8; ++i) {
            const float4 q = eq4[i];
            const int d = dh * 32 + i * 4;
            ob[(size_t)(d + 0) * 1024] = q.x;
            ob[(size_t)(d + 1) * 1024] = q.y;
            ob[(size_t)(d + 2) * 1024] = q.z;
            ob[(size_t)(d + 3) * 1024] = q.w;
        }
    }

    // ---- block partial: sum(z^2) - 2*sum(t); wave shfl-reduce
    float s = zacc - 2.f * tcon;
#pragma unroll
    for (int off = 1; off < 64; off <<= 1) s += __shfl_xor(s, off, 64);
    if (lane == 0) redw[wave] = s;
    __syncthreads();
    if (tid == 0) pP[blk] = (redw[0] + redw[1]) + (redw[2] + redw[3]);

    // ---- all partials visible after this
    grid.sync();

    // ---- phase 2: block 0 reduces 512 partials -> loss (fixed order)
    if (blk == 0) {
        red2[tid] = pP[tid] + pP[tid + 256];
        __syncthreads();
#pragma unroll
        for (int st = 128; st > 0; st >>= 1) {
            if (tid < st) red2[tid] += red2[tid + st];
            __syncthreads();
        }
        if (tid == 0)
            out[(size_t)NVEC * D] = 1.25f * red2[0] * (1.0f / (float)((size_t)NVEC * D));
    }
}

extern "C" void kernel_launch(void* const* d_in, const int* in_sizes, int n_in,
                              void* d_out, int out_size, void* d_ws, size_t ws_size,
                              hipStream_t stream) {
    const float* z   = (const float*)d_in[0];   // [64, 64, 32, 32]
    const float* emb = (const float*)d_in[1];   // [1024, 64]
    float* out = (float*)d_out;                 // 4194304 quantized + 1 loss

    char* ws = (char*)d_ws;
    unsigned* ebf_u = (unsigned*)ws;            // 128 KB bf16 codebook
    float* hb = (float*)(ws + 131072);          // 4 KB biased neg half-norms
    float* pP = (float*)(ws + 135168);          // 2 KB block partials

    void* args[] = { (void*)&z, (void*)&emb, (void*)&ebf_u,
                     (void*)&hb, (void*)&out, (void*)&pP };
    hipLaunchCooperativeKernel((const void*)vq_coop, dim3(NBLK), dim3(256),
                               args, 0, stream);
}

// Round 17
// 29.626 us; speedup vs baseline: 4.3287x; 4.3287x over previous
//
#include <hip/hip_runtime.h>

#define D 64
#define K 1024
#define NVEC 65536
#define MB 128            // vectors per block
#define NBLK (NVEC / MB)  // 512 blocks -> 2/CU
#define WAVES 4
#define KPW (K / WAVES)   // 256 codes per wave
#define TILES (KPW / 16)  // 16
#define NG (MB / 16)      // 8 vector groups
#define RING 2            // r13: depth>2 is null

typedef __attribute__((ext_vector_type(8))) short bf16x8;
typedef __attribute__((ext_vector_type(4))) float f32x4;
typedef __attribute__((ext_vector_type(4))) int i32x4;

// single v_perm_b32: {hi16(b), hi16(a)} == bf16x2(trunc(a), trunc(b))
__device__ inline unsigned pk2t(float a, float b) {
    return __builtin_amdgcn_perm(__builtin_bit_cast(unsigned, b),
                                 __builtin_bit_cast(unsigned, a), 0x07060302u);
}
__device__ inline int max3i(int a, int b, int c) {   // -> v_max3_i32
    const int m = a > b ? a : b;
    return m > c ? m : c;
}
__device__ inline float dot4(float4 v, float acc) {
    acc = fmaf(v.x, v.x, acc); acc = fmaf(v.y, v.y, acc);
    acc = fmaf(v.z, v.z, acc); acc = fmaf(v.w, v.w, acc);
    return acc;
}

// ---------------------------------------------------------------------------
// Main (prep-free): k-loop ring-prefetches RAW f32 codebook rows; per tile
// packs bf16 A-frags via v_perm and derives 1-0.5||e||^2 in-register
// (16 FMA + 2 shfl_xor + 4 shfl). r11 structure otherwise verbatim.
// ---------------------------------------------------------------------------
__global__ __launch_bounds__(256, 2) void vq_main(const float* __restrict__ z,
                                                  const float* __restrict__ emb,
                                                  float* __restrict__ out,
                                                  float* __restrict__ pP) {
    __shared__ __align__(16) char zl[MB * 128];   // 16 KB bf16 z-tile [v][d], XOR-swizzled
    __shared__ int   wv[WAVES * MB];              // 2 KB
    __shared__ int   fin[MB];
    __shared__ float redw[WAVES];

    const int tid = threadIdx.x;
    const int blk = blockIdx.x;
    const int b   = blk >> 3;              // batch (8 blocks per batch)
    const int hw0 = (blk & 7) * MB;        // first spatial pos
    const float* zb = z + (size_t)b * (D * 1024) + hw0;

    const int wave = tid >> 6;
    const int lane = tid & 63;
    const int cw   = wave * KPW;
    const int l16  = lane & 15;
    const int lg   = lane >> 4;    // 0..3

    // ---- stage z tile: f32 [d][v] -> LDS bf16 [v][d] swizzled; f32 sum(z^2)
    float zacc = 0.f;
#pragma unroll
    for (int it = 0; it < 2; ++it) {
        const int item = it * 256 + tid;   // 0..511
        const int v4 = item & 31;          // 4-vector group (128 v)
        const int d4 = item >> 5;          // 4-dim group (64 d)
        float4 r[4];
#pragma unroll
        for (int i = 0; i < 4; ++i)
            r[i] = *reinterpret_cast<const float4*>(zb + (size_t)(d4 * 4 + i) * 1024 + v4 * 4);
        const float* rf = reinterpret_cast<const float*>(r);
#pragma unroll
        for (int n = 0; n < 16; ++n) zacc = fmaf(rf[n], rf[n], zacc);
#pragma unroll
        for (int j = 0; j < 4; ++j) {
            const int v = v4 * 4 + j;
            uint2 pk;
            pk.x = pk2t(rf[0 * 4 + j], rf[1 * 4 + j]);
            pk.y = pk2t(rf[2 * 4 + j], rf[3 * 4 + j]);
            const int byte = v * 128 + ((d4 * 8) ^ ((v & 7) << 4));
            *reinterpret_cast<uint2*>(zl + byte) = pk;
        }
    }

    // ---- ring preload of RAW f32 codebook tiles 0,1 (this lane: row cw+kt*16+l16,
    //      dims {lg*8..+8} and {32+lg*8..+8} = 4 float4)
    float4 F0[RING], F1[RING], F2[RING], F3[RING];
#pragma unroll
    for (int p = 0; p < RING; ++p) {
        const float4* rp = reinterpret_cast<const float4*>(emb + (size_t)(cw + p * 16 + l16) * D);
        F0[p] = rp[lg * 2];     F1[p] = rp[lg * 2 + 1];
        F2[p] = rp[8 + lg * 2]; F3[p] = rp[8 + lg * 2 + 1];
    }
    __syncthreads();

    // ---- B-frags: this block's 128 vectors register-resident (64 VGPR)
    bf16x8 bfr[NG][2];
#pragma unroll
    for (int g = 0; g < NG; ++g)
#pragma unroll
        for (int h = 0; h < 2; ++h) {
            const int v = g * 16 + l16;
            const int byte = v * 128 + (((h * 64) + lg * 16) ^ ((v & 7) << 4));
            bfr[g][h] = *reinterpret_cast<const bf16x8*>(zl + byte);
        }

    // ---- k-loop: consume ring slot kt&1 (pack + in-reg norms), prefetch kt+2
    int best[NG];
#pragma unroll
    for (int g = 0; g < NG; ++g) best[g] = 0;

#pragma unroll 2
    for (int kt = 0; kt < TILES; ++kt) {
        const int cur = kt & (RING - 1);         // static under unroll 2
        const float4 f0 = F0[cur], f1 = F1[cur], f2 = F2[cur], f3 = F3[cur];
        const int nk = (kt + RING < TILES) ? kt + RING : kt;   // tail: harmless reload
        const float4* np = reinterpret_cast<const float4*>(emb + (size_t)(cw + nk * 16 + l16) * D);
        F0[cur] = np[lg * 2];     F1[cur] = np[lg * 2 + 1];
        F2[cur] = np[8 + lg * 2]; F3[cur] = np[8 + lg * 2 + 1];

        // pack A-frags (8x v_perm)
        i32x4 ai0 = { (int)pk2t(f0.x, f0.y), (int)pk2t(f0.z, f0.w),
                      (int)pk2t(f1.x, f1.y), (int)pk2t(f1.z, f1.w) };
        i32x4 ai1 = { (int)pk2t(f2.x, f2.y), (int)pk2t(f2.z, f2.w),
                      (int)pk2t(f3.x, f3.y), (int)pk2t(f3.z, f3.w) };
        const bf16x8 a0 = __builtin_bit_cast(bf16x8, ai0);
        const bf16x8 a1 = __builtin_bit_cast(bf16x8, ai1);

        // in-register biased neg half-norms: 1 - 0.5*||e_{cbase+lg*4+r}||^2
        float nrm = dot4(f3, dot4(f2, dot4(f1, dot4(f0, 0.f))));
        nrm += __shfl_xor(nrm, 16, 64);
        nrm += __shfl_xor(nrm, 32, 64);   // all 4 copies of row l16 summed
        f32x4 cc;
#pragma unroll
        for (int r = 0; r < 4; ++r)
            cc[r] = fmaf(-0.5f, __shfl(nrm, lg * 4 + r, 16), 1.0f);

        const int idx0 = cw + kt * 16 + lg * 4;
#pragma unroll
        for (int g = 0; g < NG; ++g) {
            f32x4 c = cc;
            c = __builtin_amdgcn_mfma_f32_16x16x32_bf16(a0, bfr[g][0], c, 0, 0, 0);
            c = __builtin_amdgcn_mfma_f32_16x16x32_bf16(a1, bfr[g][1], c, 0, 0, 0);
            const int p0 = (int)((__builtin_bit_cast(unsigned, c[0]) & 0xFFFFFC00u) | (unsigned)(idx0 + 0));
            const int p1 = (int)((__builtin_bit_cast(unsigned, c[1]) & 0xFFFFFC00u) | (unsigned)(idx0 + 1));
            const int p2 = (int)((__builtin_bit_cast(unsigned, c[2]) & 0xFFFFFC00u) | (unsigned)(idx0 + 2));
            const int p3 = (int)((__builtin_bit_cast(unsigned, c[3]) & 0xFFFFFC00u) | (unsigned)(idx0 + 3));
            best[g] = max3i(max3i(p0, p1, p2), p3, best[g]);   // 2x v_max3_i32
        }
    }

    // ---- cross-lane argmax (over lg groups)
#pragma unroll
    for (int g = 0; g < NG; ++g) {
        int tv = best[g];
        int o = __shfl_xor(tv, 16, 64); tv = tv > o ? tv : o;
        o = __shfl_xor(tv, 32, 64);     tv = tv > o ? tv : o;
        if (lane < 16) wv[wave * MB + g * 16 + l16] = tv;
    }
    __syncthreads();

    // ---- cross-wave combine; unpack winning score for the loss
    float tcon = 0.f;
    if (tid < MB) {
        int tv = wv[tid];
#pragma unroll
        for (int w = 1; w < WAVES; ++w) {
            const int o = wv[w * MB + tid];
            tv = tv > o ? tv : o;
        }
        fin[tid] = tv & (K - 1);
        tcon = __builtin_bit_cast(float, (unsigned)tv & 0xFFFFFC00u) - 1.0f;  // z.e - 0.5||e||^2
    }
    __syncthreads();

    // ---- output: gather exact f32 code rows, write out[b][d][hw] coalesced
    {
        const int v  = tid & 127;
        const int dh = tid >> 7;              // 0..1, 32 dims each
        const int idx = fin[v];
        const float4* eq4 = reinterpret_cast<const float4*>(emb + (size_t)idx * D + dh * 32);
        float* ob = out + (size_t)b * (D * 1024) + hw0 + v;
#pragma unroll
        for (int i = 0; i < 8; ++i) {
            const float4 q = eq4[i];
            const int d = dh * 32 + i * 4;
            ob[(size_t)(d + 0) * 1024] = q.x;
            ob[(size_t)(d + 1) * 1024] = q.y;
            ob[(size_t)(d + 2) * 1024] = q.z;
            ob[(size_t)(d + 3) * 1024] = q.w;
        }
    }

    // ---- block partial: sum(z^2) - 2*sum(t); wave shfl-reduce + 1 barrier
    float s = zacc - 2.f * tcon;
#pragma unroll
    for (int off = 1; off < 64; off <<= 1) s += __shfl_xor(s, off, 64);
    if (lane == 0) redw[wave] = s;
    __syncthreads();
    if (tid == 0) pP[blk] = (redw[0] + redw[1]) + (redw[2] + redw[3]);
}

// ---------------------------------------------------------------------------
// Loss epilogue: 1 block; kernel boundary guarantees pP visibility.
// ---------------------------------------------------------------------------
__global__ __launch_bounds__(256) void vq_loss(const float* __restrict__ pP,
                                               float* __restrict__ loss_out) {
    __shared__ float red[256];
    float s = 0.f;
    for (int i = threadIdx.x; i < NBLK; i += 256) s += pP[i];
    red[threadIdx.x] = s;
    __syncthreads();
#pragma unroll
    for (int st = 128; st > 0; st >>= 1) {
        if (threadIdx.x < st) red[threadIdx.x] += red[threadIdx.x + st];
        __syncthreads();
    }
    if (threadIdx.x == 0)
        loss_out[0] = 1.25f * red[0] * (1.0f / (float)((size_t)NVEC * D));
}

extern "C" void kernel_launch(void* const* d_in, const int* in_sizes, int n_in,
                              void* d_out, int out_size, void* d_ws, size_t ws_size,
                              hipStream_t stream) {
    const float* z   = (const float*)d_in[0];   // [64, 64, 32, 32]
    const float* emb = (const float*)d_in[1];   // [1024, 64]
    float* out = (float*)d_out;                 // 4194304 quantized + 1 loss

    float* pP = (float*)d_ws;                   // 512 block partials

    vq_main<<<NBLK, 256, 0, stream>>>(z, emb, out, pP);
    vq_loss<<<1, 256, 0, stream>>>(pP, out + (size_t)NVEC * D);
}